// Round 2
// baseline (33.859 us; speedup 1.0000x reference)
//
#include <hip/hip_runtime.h>
#include <hip/hip_bf16.h>

#define L_ 30
#define NB 2
#define NN 64
#define NM 64
#define MCH 16
#define CHUNKS 4

// workspace float offsets
#define O_BOP  0        // 128
#define O_WEWK 128      // 4x128
#define O_CK   640      // 30x128  [l][c]
#define O_QS   4480     // 128x128 (q * 1/sqrt(dh))
#define O_G    20864    // ushort[136][128] packed in float area (8704 floats)

__device__ __forceinline__ unsigned short f2b(float v) {
    union { float f; unsigned int u; } x; x.f = v;
    unsigned int u = x.u + 0x7FFFu + ((x.u >> 16) & 1u);   // round-to-nearest-even
    return (unsigned short)(u >> 16);
}
__device__ __forceinline__ float b2f(unsigned short s) {
    union { unsigned int u; float f; } x; x.u = ((unsigned int)s) << 16; return x.f;
}
__device__ __forceinline__ float b2f_lo(unsigned int p) {
    union { unsigned int u; float f; } x; x.u = p << 16; return x.f;
}
__device__ __forceinline__ float b2f_hi(unsigned int p) {
    union { unsigned int u; float f; } x; x.u = p & 0xFFFF0000u; return x.f;
}

// One block per output column e (128 blocks). All precompute is column-parallel:
//   wop_col[c]   = (Wo @ Wp[:,e])[c]
//   wvop_h[d]    = sum_{c in head h} Wv[d][c] * wop_col[c]
//   P[(h,j)][e]  = sum_d We[j][d] * wvop_h[d]
//   D[(l,h)][e]  = sum_d (be+pe_l)[d] * wvop_h[d] + sum_{c in h} bv[c]*wop_col[c]
//   Ck[l][e]     = (be+pe_l) @ Wk[:,e] + bk[e]
//   WeWk[j][e]   = We[j] @ Wk[:,e]
//   qs[r][e]     = (afeat[r] @ (Wa@Wq)[:,e] + ba@Wq[:,e] + bq[e]) / sqrt(32)
//   bop[e]       = bo @ wop_col + bp[e]
__global__ __launch_bounds__(256)
void k_pre(const float* __restrict__ agent,
           const float* __restrict__ We,  const float* __restrict__ be,
           const float* __restrict__ Wa,  const float* __restrict__ ba,
           const float* __restrict__ pe,
           const float* __restrict__ Wq,  const float* __restrict__ bq,
           const float* __restrict__ Wk,  const float* __restrict__ bk,
           const float* __restrict__ Wv,  const float* __restrict__ bv,
           const float* __restrict__ Wo,  const float* __restrict__ bo,
           const float* __restrict__ Wp,  const float* __restrict__ bp,
           float* __restrict__ ws) {
    const int e = blockIdx.x;
    const int t = threadIdx.x;
    __shared__ float wp_s[128], wk_s[128], wq_s[128];
    __shared__ float pesum[30][132];     // be + pe[l], padded stride 132
    __shared__ float wop_s[128];
    __shared__ float wvop_s[4][132];
    __shared__ float wawq_s[12];
    __shared__ float bqq_s;
    __shared__ float dbv_s[4];

    // phase 0: stage weight columns + pesum
    if (t < 128) { wp_s[t] = Wp[t*128+e]; wq_s[t] = Wq[t*128+e]; }
    else         { int d = t-128; wk_s[d] = Wk[d*128+e]; }
    for (int idx = t; idx < 30*128; idx += 256) {
        int l = idx >> 7, d = idx & 127;
        pesum[l][d] = be[d] + pe[l*128+d];
    }
    __syncthreads();

    // phase 1: wop_col, Ck, WaWq, bqq, WeWk
    if (t < 128) {
        float a = 0.f;
        const float* wo = Wo + t*128;
        #pragma unroll 8
        for (int x = 0; x < 128; ++x) a += wo[x]*wp_s[x];
        wop_s[t] = a;
    } else if (t < 158) {
        int l = t-128;
        float a = bk[e];
        #pragma unroll 8
        for (int d = 0; d < 128; ++d) a += pesum[l][d]*wk_s[d];
        ws[O_CK + l*128 + e] = a;
    } else if (t < 170) {
        int f = t-158;
        float a = 0.f;
        #pragma unroll 8
        for (int d = 0; d < 128; ++d) a += Wa[f*128+d]*wq_s[d];
        wawq_s[f] = a;
    } else if (t == 170) {
        float a = bq[e];
        for (int d = 0; d < 128; ++d) a += ba[d]*wq_s[d];
        bqq_s = a;
    } else if (t >= 172 && t < 176) {
        int j = t-172;
        float a = 0.f;
        #pragma unroll 8
        for (int d = 0; d < 128; ++d) a += We[j*128+d]*wk_s[d];
        ws[O_WEWK + j*128 + e] = a;
    }
    __syncthreads();

    // phase 2: wvop (512 jobs), qs, dbv, bop
    {
        #pragma unroll
        for (int k = 0; k < 2; ++k) {
            int job = t*2 + k;
            int h = job & 3, d = job >> 2;
            float a = 0.f;
            const float* wv = Wv + d*128 + h*32;
            const float* wc = &wop_s[h*32];
            #pragma unroll 8
            for (int c = 0; c < 32; ++c) a += wv[c]*wc[c];
            wvop_s[h][d] = a;
        }
    }
    if (t < 128) {              // qs[r][e]
        float a = bqq_s;
        const float* ag = agent + t*16;
        a += ag[2]*wawq_s[0];
        #pragma unroll
        for (int f = 1; f < 12; ++f) a += ag[4+f]*wawq_s[f];
        ws[O_QS + t*128 + e] = a * 0.17677669529663687f;
    } else if (t < 132) {       // dbv[h]
        int h = t-128;
        float a = 0.f;
        for (int c = 0; c < 32; ++c) a += bv[h*32+c]*wop_s[h*32+c];
        dbv_s[h] = a;
    } else if (t == 132) {      // bop[e]
        float a = bp[e];
        for (int c = 0; c < 128; ++c) a += bo[c]*wop_s[c];
        ws[O_BOP + e] = a;
    }
    __syncthreads();

    // phase 3: G rows (bf16), final layout: row<16 -> P[h*4+j], row>=16 -> 16+h*30+l
    unsigned short* G = (unsigned short*)(ws + O_G);
    if (t < 16) {
        int h = t >> 2, j = t & 3;
        float a = 0.f;
        #pragma unroll 8
        for (int d = 0; d < 128; ++d) a += We[j*128+d]*wvop_s[h][d];
        G[t*128 + e] = f2b(a);
    } else if (t < 136) {
        int r = t-16; int h = r/30, l = r - h*30;
        float a = dbv_s[h];
        #pragma unroll 8
        for (int d = 0; d < 128; ++d) a += pesum[l][d]*wvop_s[h][d];
        G[t*128 + e] = f2b(a);
    }
}

__global__ __launch_bounds__(256)
void k_main(const float* __restrict__ agent, const float* __restrict__ lane,
            const float* __restrict__ ws, float* __restrict__ out) {

    __shared__ float u_s[16];
    __shared__ float c_s[120];
    __shared__ __align__(16) unsigned short G_s[136][128];   // bf16 [P;D]
    __shared__ __align__(16) unsigned short edge_s[MCH][30][4];
    __shared__ __align__(16) float Wc_s[MCH][140];           // [0..16)=we4, [16..136)=w

    const int t = threadIdx.x;
    const int bid = blockIdx.x;
    const int bn = bid >> 2;            // b*64+n
    const int chunk = bid & 3;
    const int b = bn >> 6;
    const int m0 = chunk * MCH;

    // stage G (pre-converted bf16, final layout): plain vector copy, 34816 B
    {
        const uint4* src = (const uint4*)(ws + O_G);
        uint4* dst = (uint4*)&G_s[0][0];
        #pragma unroll
        for (int idx = t; idx < 136*128*2/16; idx += 256) dst[idx] = src[idx];
    }
    // per-agent u (4x4) and c (4x30)
    if (t < 136) {
        const float* q = ws + O_QS + bn*128;
        if (t < 16) {
            int h = t >> 2, j = t & 3;
            const float* wk = ws + O_WEWK + j*128 + h*32;
            const float* qh = q + h*32;
            float a = 0.f;
            #pragma unroll 8
            for (int d = 0; d < 32; ++d) a += wk[d] * qh[d];
            u_s[t] = a;
        } else {
            int r = t - 16; int h = r / 30, l = r - h*30;
            const float* ck = ws + O_CK + l*128 + h*32;
            const float* qh = q + h*32;
            float a = 0.f;
            #pragma unroll 8
            for (int d = 0; d < 32; ++d) a += ck[d] * qh[d];
            c_s[r] = a;
        }
    }
    const float ax  = agent[bn*16+0], ay = agent[bn*16+1];
    const float as_ = agent[bn*16+3], ac = agent[bn*16+4];
    const float f1 = (ax==0.f && ay==0.f && as_==0.f && ac==0.f) ? 0.f : 1.f;
    __syncthreads();

    // B1: edges (bf16 to LDS) + raw scores into Wc_s[m][16+h*30+l]
    for (int job = t; job < MCH*30; job += 256) {
        int m = job / 30, l = job - m*30;
        const float* lp = lane + (size_t)((b*NM + m0 + m)*L_ + l)*4;
        float4 lv = *(const float4*)lp;
        float f2 = (lv.x==0.f && lv.y==0.f && lv.z==0.f && lv.w==0.f) ? 0.f : 1.f;
        float f = f1 * f2;
        float dx = lv.x - ax, dy = lv.y - ay;
        float rx = (ac*dx + as_*dy) * 0.1f * f;
        float ry = (ac*dy - as_*dx) * 0.1f * f;
        float rs = (lv.z*ac - lv.w*as_) * f;
        float rc = (lv.w*ac + lv.z*as_) * f;
        unsigned int p0 = (unsigned int)f2b(rx) | ((unsigned int)f2b(ry) << 16);
        unsigned int p1 = (unsigned int)f2b(rs) | ((unsigned int)f2b(rc) << 16);
        *(uint2*)&edge_s[m][l][0] = make_uint2(p0, p1);
        #pragma unroll
        for (int h = 0; h < 4; ++h) {
            float s = rx*u_s[h*4+0] + ry*u_s[h*4+1] + rs*u_s[h*4+2] + rc*u_s[h*4+3]
                    + c_s[h*30+l];
            Wc_s[m][16 + h*30 + l] = s;
        }
    }
    __syncthreads();
    // B2: softmax over l per (m,h)
    if (t < MCH*4) {
        int m = t >> 2, h = t & 3;
        float* s = &Wc_s[m][16 + h*30];
        float mx = s[0];
        for (int l = 1; l < 30; ++l) mx = fmaxf(mx, s[l]);
        float sum = 0.f;
        for (int l = 0; l < 30; ++l) { float e = __expf(s[l]-mx); s[l] = e; sum += e; }
        float inv = 1.f / sum;
        for (int l = 0; l < 30; ++l) s[l] *= inv;
    }
    __syncthreads();
    // B3: we4[m][h*4+j] = sum_l w * edge_j   (256 jobs exactly)
    {
        int m = t >> 4, i = t & 15;
        int h = i >> 2, j = i & 3;
        float a = 0.f;
        for (int l = 0; l < 30; ++l)
            a += Wc_s[m][16 + h*30 + l] * b2f(edge_s[m][l][j]);
        Wc_s[m][i] = a;
    }
    __syncthreads();
    // C: OUT[16m x 128e] = Wc[16x136] @ G[136x128] + bop ; tile 2m x 4e per thread
    {
        const int em = t & 31, r = t >> 5;
        const int e0 = em * 4;
        const int mA = r, mB = r + 8;
        float4 bb = *(const float4*)(ws + O_BOP + e0);
        float aA0=bb.x,aA1=bb.y,aA2=bb.z,aA3=bb.w;
        float aB0=bb.x,aB1=bb.y,aB2=bb.z,aB3=bb.w;
        for (int i = 0; i < 136; i += 4) {
            float4 wa = *(const float4*)&Wc_s[mA][i];
            float4 wb = *(const float4*)&Wc_s[mB][i];
            float wav[4] = {wa.x, wa.y, wa.z, wa.w};
            float wbv[4] = {wb.x, wb.y, wb.z, wb.w};
            #pragma unroll
            for (int di = 0; di < 4; ++di) {
                uint2 g = *(const uint2*)&G_s[i+di][e0];
                float g0 = b2f_lo(g.x), g1 = b2f_hi(g.x);
                float g2 = b2f_lo(g.y), g3 = b2f_hi(g.y);
                aA0 += wav[di]*g0; aA1 += wav[di]*g1; aA2 += wav[di]*g2; aA3 += wav[di]*g3;
                aB0 += wbv[di]*g0; aB1 += wbv[di]*g1; aB2 += wbv[di]*g2; aB3 += wbv[di]*g3;
            }
        }
        size_t baseA = ((size_t)(bn*NM + m0 + mA))*128 + e0;
        size_t baseB = ((size_t)(bn*NM + m0 + mB))*128 + e0;
        *(float4*)(out + baseA) = make_float4(aA0,aA1,aA2,aA3);
        *(float4*)(out + baseB) = make_float4(aB0,aB1,aB2,aB3);
    }
}

extern "C" void kernel_launch(void* const* d_in, const int* in_sizes, int n_in,
                              void* d_out, int out_size, void* d_ws, size_t ws_size,
                              hipStream_t stream) {
    const float* agent = (const float*)d_in[0];
    const float* lane  = (const float*)d_in[1];
    const float* We = (const float*)d_in[2];
    const float* be = (const float*)d_in[3];
    const float* Wa = (const float*)d_in[4];
    const float* ba = (const float*)d_in[5];
    const float* pe = (const float*)d_in[6];
    const float* Wq = (const float*)d_in[7];
    const float* bq = (const float*)d_in[8];
    const float* Wk = (const float*)d_in[9];
    const float* bk = (const float*)d_in[10];
    const float* Wv = (const float*)d_in[11];
    const float* bv = (const float*)d_in[12];
    const float* Wo = (const float*)d_in[13];
    const float* bo = (const float*)d_in[14];
    const float* Wp = (const float*)d_in[15];
    const float* bp = (const float*)d_in[16];
    float* ws  = (float*)d_ws;
    float* out = (float*)d_out;

    hipLaunchKernelGGL(k_pre, dim3(128), dim3(256), 0, stream,
                       agent, We, be, Wa, ba, pe, Wq, bq, Wk, bk, Wv, bv,
                       Wo, bo, Wp, bp, ws);
    hipLaunchKernelGGL(k_main, dim3(NB*NN*CHUNKS), dim3(256), 0, stream,
                       agent, lane, ws, out);
}